// Round 2
// baseline (510.164 us; speedup 1.0000x reference)
//
#include <hip/hip_runtime.h>

// SeqFCEncoder: out = relu(drop(x) @ W1 + b1) @ W2 + b2
// B=262144 rows, L=50 (K-padded to 64), H=1024 (16 chunks of 64), E=256.
// bf16 MFMA 16x16x32 fused pipeline; weights pre-packed into fragment order in ws.
// Dropout: JAX threefry2x32, jax_threefry_partitionable=True semantics:
//   per flat element j: counter words (hi=0, lo=j), key (0,42), bits = out0 ^ out1.

typedef __attribute__((ext_vector_type(8))) short short8;   // 8 bf16 = one MFMA operand frag
typedef __attribute__((ext_vector_type(4))) float f32x4;    // MFMA accumulator frag

__device__ __forceinline__ unsigned short f2bf(float f) {
  unsigned u = __float_as_uint(f);
  u += 0x7fffu + ((u >> 16) & 1u);           // round-to-nearest-even
  return (unsigned short)(u >> 16);
}

__device__ __forceinline__ unsigned rotl_(unsigned x, int d) {
  return (x << d) | (x >> (32 - d));
}

// Partitionable threefry2x32: key=(0,42), counter=(0, j); 20 rounds; bits=v0^v1.
// uniform: bitcast((bits>>9)|0x3f800000) - 1.0f;  drop iff u < 0.2f
__device__ __forceinline__ bool drop_rand(unsigned j) {
  const unsigned k0 = 0u, k1 = 42u, k2 = 0x1BD11BDAu ^ 42u;
  unsigned v0 = 0u + k0;          // counter hi word = 0
  unsigned v1 = j + k1;           // counter lo word = flat index
#define MIX(rot) { v0 += v1; v1 = rotl_(v1, rot); v1 ^= v0; }
  MIX(13) MIX(15) MIX(26) MIX(6)   v0 += k1; v1 += k2 + 1u;
  MIX(17) MIX(29) MIX(16) MIX(24)  v0 += k2; v1 += k0 + 2u;
  MIX(13) MIX(15) MIX(26) MIX(6)   v0 += k0; v1 += k1 + 3u;
  MIX(17) MIX(29) MIX(16) MIX(24)  v0 += k1; v1 += k2 + 4u;
  MIX(13) MIX(15) MIX(26) MIX(6)   v0 += k2; v1 += k0 + 5u;
#undef MIX
  unsigned bits = v0 ^ v1;
  float u = __uint_as_float((bits >> 9) | 0x3f800000u) - 1.0f;
  return u < 0.2f;
}

// ---------------------------------------------------------------------------
// Prep: pack W1 (50x1024, K-padded to 64) and W2 (1024x256) as bf16 in MFMA
// B-fragment order. Fragment (lane, j) holds W[kblk*32 + (lane>>4)*8 + j][nt*16 + (lane&15)].
//   pW1 @ ws[0]:      [nblk 0..63][kb 0..1][lane][j]          = 65536 elems (128 KB)
//   pW2 @ ws[65536]:  [c 0..15][kb 0..1][nt 0..15][lane][j]   = 262144 elems (512 KB)
// ---------------------------------------------------------------------------
__global__ void pack_weights(const float* __restrict__ W1, const float* __restrict__ W2,
                             unsigned short* __restrict__ ws) {
  int t = blockIdx.x * 256 + threadIdx.x;   // 0..40959
  if (t < 8192) {
    int nblk = t >> 7, kb = (t >> 6) & 1, lane = t & 63;
    int kbase = kb * 32 + ((lane >> 4) * 8);
    int col = nblk * 16 + (lane & 15);
    short8 vv;
#pragma unroll
    for (int j = 0; j < 8; ++j) {
      int k = kbase + j;
      vv[j] = (short)((k < 50) ? f2bf(W1[k * 1024 + col]) : (unsigned short)0);
    }
    *(short8*)&ws[t * 8] = vv;
  } else {
    int t2 = t - 8192;                       // 0..32767
    int c = t2 >> 11, kb = (t2 >> 10) & 1, nt = (t2 >> 6) & 15, lane = t2 & 63;
    int kbase = c * 64 + kb * 32 + ((lane >> 4) * 8);
    int e = nt * 16 + (lane & 15);
    short8 vv;
#pragma unroll
    for (int j = 0; j < 8; ++j) vv[j] = (short)f2bf(W2[(size_t)(kbase + j) * 256 + e]);
    *(short8*)&ws[65536 + t2 * 8] = vv;
  }
}

// ---------------------------------------------------------------------------
// Fused MLP. 512 threads (8 waves), 128 rows/block, grid 2048.
// LDS: x tile [mblk8][kb2][lane][j] 16KB | h chunk [mblk8][kb2][lane][j] 16KB
//      | W2 chunk [kb2][nt16][lane][j] 32KB  => 64 KB total.
// Per chunk c (H cols [64c,64c+64)):
//   prefetch W2 chunk to regs -> barrier -> GEMM1 (x@W1 frag-from-global)
//   + bias/relu/bf16 -> lds_h -> commit W2 regs -> lds -> barrier -> GEMM2 accum.
// ---------------------------------------------------------------------------
__global__ __launch_bounds__(512, 2) void mlp_fused(
    const float* __restrict__ seq, const float* __restrict__ b1,
    const float* __restrict__ b2, const unsigned short* __restrict__ ws,
    float* __restrict__ out) {
  __shared__ __align__(16) unsigned short lds_x[8192];
  __shared__ __align__(16) unsigned short lds_h[8192];
  __shared__ __align__(16) unsigned short lds_w2[16384];

  const int tid  = threadIdx.x;
  const int lane = tid & 63;
  const int wave = tid >> 6;
  const int quad = lane >> 4;
  const int l15  = lane & 15;
  const int m0   = blockIdx.x * 128;
  const unsigned short* pW1 = ws;
  const unsigned short* pW2 = ws + 65536;

  // ---- phase 0: load x rows, first_neg scan, threefry dropout, bf16 -> lds_x
  {
    int r = tid >> 2, q = tid & 3;           // 4 threads per row, 16 elems each
    int grow = m0 + r;
    const float* xrow = seq + (size_t)grow * 50;
    float xv[16];
    unsigned negm = 0;
#pragma unroll
    for (int i = 0; i < 16; ++i) {
      int l = q * 16 + i;
      float v = (l < 50) ? xrow[l] : 0.0f;   // K-pad with 0
      xv[i] = v;
      if (v == -1.0f) negm |= (1u << i);
    }
    unsigned long long rm = ((unsigned long long)negm) << (q * 16);
    rm |= __shfl_xor(rm, 1);                 // quarters of one row are adjacent lanes
    rm |= __shfl_xor(rm, 2);
    int fn = rm ? __builtin_ctzll(rm) : 64;  // first_neg (>=50 means all valid)
    unsigned jbase = (unsigned)grow * 50u;
#pragma unroll
    for (int g = 0; g < 2; ++g) {
      short8 vv;
#pragma unroll
      for (int i = 0; i < 8; ++i) {
        int l = q * 16 + g * 8 + i;
        float v = xv[g * 8 + i];
        if (l < fn && l < 50 && drop_rand(jbase + (unsigned)l)) v = 0.0f;
        vv[i] = (short)f2bf(v);
      }
      int kq = q * 2 + g;                    // k-octet 0..7
      int idx = (((r >> 4) * 2 + (kq >> 2)) * 64 + (kq & 3) * 16 + (r & 15)) * 8;
      *(short8*)&lds_x[idx] = vv;
    }
  }

  f32x4 acc[4][4];
#pragma unroll
  for (int mi = 0; mi < 4; ++mi)
#pragma unroll
    for (int ni = 0; ni < 4; ++ni) acc[mi][ni] = f32x4{0.f, 0.f, 0.f, 0.f};

  const int w1m = wave >> 1, w1n = wave & 1;  // GEMM1: wave tile 32 rows x 32 H-cols
  const int gm  = wave >> 2, gn  = wave & 3;  // GEMM2: wave tile 64 rows x 64 E-cols

  for (int c = 0; c < 16; ++c) {
    // prefetch W2 chunk (32 KB) into registers; overlaps prev chunk's GEMM2
    short8 stg[4];
#pragma unroll
    for (int it = 0; it < 4; ++it)
      stg[it] = *(const short8*)&pW2[(size_t)c * 16384 + (size_t)(it * 512 + tid) * 8];

    __syncthreads();  // prev GEMM2 done with lds_h / lds_w2; lds_x visible (c==0)

    // ---- GEMM1: h = x @ W1[:, 64c..64c+64), B-frags streamed from global (L1/L2-hot)
    f32x4 hacc[2][2];
#pragma unroll
    for (int mi = 0; mi < 2; ++mi)
#pragma unroll
      for (int ni = 0; ni < 2; ++ni) hacc[mi][ni] = f32x4{0.f, 0.f, 0.f, 0.f};
#pragma unroll
    for (int kb = 0; kb < 2; ++kb) {
      short8 xa[2], wb[2];
#pragma unroll
      for (int mi = 0; mi < 2; ++mi)
        xa[mi] = *(const short8*)&lds_x[(size_t)(((w1m * 2 + mi) * 2 + kb) * 64 + lane) * 8];
#pragma unroll
      for (int ni = 0; ni < 2; ++ni)
        wb[ni] = *(const short8*)&pW1[(size_t)(((c * 4 + w1n * 2 + ni) * 2 + kb) * 64 + lane) * 8];
#pragma unroll
      for (int mi = 0; mi < 2; ++mi)
#pragma unroll
        for (int ni = 0; ni < 2; ++ni)
          hacc[mi][ni] = __builtin_amdgcn_mfma_f32_16x16x32_bf16(xa[mi], wb[ni], hacc[mi][ni], 0, 0, 0);
    }
    // bias + relu + bf16, C-layout (row=quad*4+r, col=l15) -> A-frag layout in lds_h
#pragma unroll
    for (int ni = 0; ni < 2; ++ni) {
      int ntg = w1n * 2 + ni;
      int khl = ntg * 16 + l15;              // 0..63 within chunk
      float b1v = b1[c * 64 + khl];
      int kb2 = ntg >> 1;
      int quad2 = ((ntg & 1) << 1) | (l15 >> 3);
      int jj = l15 & 7;
#pragma unroll
      for (int mi = 0; mi < 2; ++mi) {
        int mblk = w1m * 2 + mi;
#pragma unroll
        for (int r = 0; r < 4; ++r) {
          float v = fmaxf(hacc[mi][ni][r] + b1v, 0.0f);
          lds_h[(size_t)((mblk * 2 + kb2) * 64 + quad2 * 16 + quad * 4 + r) * 8 + jj] = f2bf(v);
        }
      }
    }
    // commit prefetched W2 chunk to LDS
#pragma unroll
    for (int it = 0; it < 4; ++it)
      *(short8*)&lds_w2[(size_t)(it * 512 + tid) * 8] = stg[it];

    __syncthreads();  // lds_h + lds_w2 ready

    // ---- GEMM2: acc += h_chunk @ W2[64c..64c+64, :]
#pragma unroll
    for (int kb = 0; kb < 2; ++kb) {
      short8 ha[4], wb2[4];
#pragma unroll
      for (int mi = 0; mi < 4; ++mi)
        ha[mi] = *(const short8*)&lds_h[(size_t)(((gm * 4 + mi) * 2 + kb) * 64 + lane) * 8];
#pragma unroll
      for (int ni = 0; ni < 4; ++ni)
        wb2[ni] = *(const short8*)&lds_w2[(size_t)((kb * 16 + gn * 4 + ni) * 64 + lane) * 8];
#pragma unroll
      for (int mi = 0; mi < 4; ++mi)
#pragma unroll
        for (int ni = 0; ni < 4; ++ni)
          acc[mi][ni] = __builtin_amdgcn_mfma_f32_16x16x32_bf16(ha[mi], wb2[ni], acc[mi][ni], 0, 0, 0);
    }
  }

  // ---- epilogue: + b2, fp32 store (C-layout: 4-row x 16-col segments)
#pragma unroll
  for (int ni = 0; ni < 4; ++ni) {
    int e = (gn * 4 + ni) * 16 + l15;
    float b2v = b2[e];
#pragma unroll
    for (int mi = 0; mi < 4; ++mi) {
      int mrow = m0 + (gm * 4 + mi) * 16 + quad * 4;
#pragma unroll
      for (int r = 0; r < 4; ++r)
        out[(size_t)(mrow + r) * 256 + e] = acc[mi][ni][r] + b2v;
    }
  }
}

extern "C" void kernel_launch(void* const* d_in, const int* in_sizes, int n_in,
                              void* d_out, int out_size, void* d_ws, size_t ws_size,
                              hipStream_t stream) {
  const float* seq = (const float*)d_in[0];
  const float* W1  = (const float*)d_in[1];
  const float* b1  = (const float*)d_in[2];
  const float* W2  = (const float*)d_in[3];
  const float* b2  = (const float*)d_in[4];
  unsigned short* ws = (unsigned short*)d_ws;   // 655360 bytes used
  float* out = (float*)d_out;

  hipLaunchKernelGGL(pack_weights, dim3(160), dim3(256), 0, stream, W1, W2, ws);
  hipLaunchKernelGGL(mlp_fused, dim3(2048), dim3(512), 0, stream, seq, b1, b2, ws, out);
}